// Round 2
// baseline (581.037 us; speedup 1.0000x reference)
//
#include <hip/hip_runtime.h>

#define NS 10  // neighbor samples per layer

// ---- gather (+ optional mean): f32 table rows -> f32 out, 4 cols/thread ----
__global__ __launch_bounds__(256) void gather_mean_k(
    float* __restrict__ out, const float* __restrict__ table,
    const int* __restrict__ idx, int M, int D4, int ns, float inv) {
  int t = blockIdx.x * 256 + threadIdx.x;
  if (t >= M * D4) return;
  int m = t / D4;
  int d4 = t - m * D4;
  long D = (long)D4 * 4;
  const int* ip = idx + (long)m * ns;
  float ax = 0.f, ay = 0.f, az = 0.f, aw = 0.f;
  for (int s = 0; s < ns; ++s) {
    long r = ip[s];
    float4 v = *(const float4*)(table + r * D + d4 * 4);
    ax += v.x; ay += v.y; az += v.z; aw += v.w;
  }
  float4 o; o.x = ax * inv; o.y = ay * inv; o.z = az * inv; o.w = aw * inv;
  ((float4*)out)[(long)m * D4 + d4] = o;
}

// ---- mean over NS consecutive rows (f32 -> f32) ----
__global__ __launch_bounds__(256) void mean_rows_k(
    float* __restrict__ out, const float* __restrict__ in, int M, int D4) {
  int t = blockIdx.x * 256 + threadIdx.x;
  if (t >= M * D4) return;
  int m = t / D4;
  int d4 = t - m * D4;
  const float4* ip = (const float4*)in;
  float ax = 0.f, ay = 0.f, az = 0.f, aw = 0.f;
  for (int s = 0; s < NS; ++s) {
    float4 v = ip[(long)(m * NS + s) * D4 + d4];
    ax += v.x; ay += v.y; az += v.z; aw += v.w;
  }
  float4 o; o.x = ax * 0.1f; o.y = ay * 0.1f; o.z = az * 0.1f; o.w = aw * 0.1f;
  ((float4*)out)[(long)m * D4 + d4] = o;
}

// ---- fused 3-segment GEMM: C[M,N] = act(sum_seg A_seg[map(r),:] @ W_seg + bias)
// A segs: f32 compact [M_A, K_seg]; W segs: f32 [K_seg, N]; row map r -> r/dv.
// BM=BN=64, BK=32, 256 threads, 4x4 per thread.
template<int ACT, bool BIAS>  // ACT: 0 none, 1 relu, 2 tanh
__global__ __launch_bounds__(256) void gemm3_k(
    const float* __restrict__ A0, const float* __restrict__ W0, int K0, int dv0,
    const float* __restrict__ A1, const float* __restrict__ W1, int K1, int dv1,
    const float* __restrict__ A2, const float* __restrict__ W2, int K2, int dv2,
    const float* __restrict__ bias, float* __restrict__ C, int N) {
  __shared__ __align__(16) float As[32][68];  // k-major, padded
  __shared__ __align__(16) float Bs[32][64];
  int tid = threadIdx.x;
  int n0 = blockIdx.x * 64, m0 = blockIdx.y * 64;
  int tx = tid & 15, ty = tid >> 4;
  float acc[4][4];
#pragma unroll
  for (int i = 0; i < 4; ++i)
#pragma unroll
    for (int j = 0; j < 4; ++j) acc[i][j] = 0.f;

  const float* Aseg[3] = {A0, A1, A2};
  const float* Wseg[3] = {W0, W1, W2};
  const int Kseg[3] = {K0, K1, K2};
  const int Dseg[3] = {dv0, dv1, dv2};

  for (int sg = 0; sg < 3; ++sg) {
    const float* A = Aseg[sg];
    const float* W = Wseg[sg];
    const int K = Kseg[sg], dv = Dseg[sg];
    for (int k0 = 0; k0 < K; k0 += 32) {
      // A tile: 64 rows x 32 k, 2 float4 per thread, store transposed to LDS
#pragma unroll
      for (int l = 0; l < 2; ++l) {
        int e = tid + l * 256;
        int row = e >> 3, c4 = e & 7;
        int gr = m0 + row;
        int ar = (dv > 1) ? (gr / dv) : gr;
        float4 v = *(const float4*)(A + (long)ar * K + k0 + c4 * 4);
        As[c4 * 4 + 0][row] = v.x; As[c4 * 4 + 1][row] = v.y;
        As[c4 * 4 + 2][row] = v.z; As[c4 * 4 + 3][row] = v.w;
      }
      // B tile: 32 k x 64 n
#pragma unroll
      for (int l = 0; l < 2; ++l) {
        int e = tid + l * 256;
        int row = e >> 4, c4 = e & 15;
        float4 v = *(const float4*)(W + (long)(k0 + row) * N + n0 + c4 * 4);
        *(float4*)&Bs[row][c4 * 4] = v;
      }
      __syncthreads();
#pragma unroll
      for (int kk = 0; kk < 32; ++kk) {
        float4 a = *(const float4*)&As[kk][ty * 4];
        float4 b = *(const float4*)&Bs[kk][tx * 4];
        float av[4] = {a.x, a.y, a.z, a.w};
        float bv[4] = {b.x, b.y, b.z, b.w};
#pragma unroll
        for (int i = 0; i < 4; ++i)
#pragma unroll
          for (int j = 0; j < 4; ++j)
            acc[i][j] = fmaf(av[i], bv[j], acc[i][j]);
      }
      __syncthreads();
    }
  }
#pragma unroll
  for (int i = 0; i < 4; ++i) {
    long row = m0 + ty * 4 + i;
#pragma unroll
    for (int j = 0; j < 4; ++j) {
      int col = n0 + tx * 4 + j;
      float v = acc[i][j];
      if (BIAS) v += bias[col];
      if (ACT == 1) v = fmaxf(v, 0.f);
      if (ACT == 2) v = tanhf(v);
      C[row * N + col] = v;
    }
  }
}

// ---- finalize: out = normalize((o0+o1)/2) @ fc_w + fc_b, f32 out ----
__global__ __launch_bounds__(64) void finalize_k(
    const float* __restrict__ o0, const float* __restrict__ o1,
    const float* __restrict__ fcw, const float* __restrict__ fcb,
    float* __restrict__ out) {
  int b = blockIdx.x, l = threadIdx.x;
  float v[4];
  float ss = 0.f;
#pragma unroll
  for (int k = 0; k < 4; ++k) {
    int j = l + 64 * k;
    v[k] = 0.5f * (o0[(long)b * 256 + j] + o1[(long)b * 256 + j]);
    ss += v[k] * v[k];
  }
#pragma unroll
  for (int off = 32; off > 0; off >>= 1) ss += __shfl_down(ss, off);
  ss = __shfl(ss, 0);
  float sc = 1.f / fmaxf(sqrtf(ss), 1e-12f);
  float p[8];
#pragma unroll
  for (int c = 0; c < 8; ++c) p[c] = 0.f;
#pragma unroll
  for (int k = 0; k < 4; ++k) {
    int j = l + 64 * k;
    float vh = v[k] * sc;
#pragma unroll
    for (int c = 0; c < 8; ++c) p[c] += vh * fcw[j * 8 + c];
  }
#pragma unroll
  for (int off = 32; off > 0; off >>= 1) {
#pragma unroll
    for (int c = 0; c < 8; ++c) p[c] += __shfl_down(p[c], off);
  }
  if (l == 0) {
#pragma unroll
    for (int c = 0; c < 8; ++c) out[b * 8 + c] = p[c] + fcb[c];
  }
}

extern "C" void kernel_launch(void* const* d_in, const int* in_sizes, int n_in,
                              void* d_out, int out_size, void* d_ws, size_t ws_size,
                              hipStream_t stream) {
  const int* ids = (const int*)d_in[0];
  const float* feats = (const float*)d_in[1];
  const int* nidx0[2] = {(const int*)d_in[2], (const int*)d_in[4]};
  const int* nidx1[2] = {(const int*)d_in[3], (const int*)d_in[5]};
  const int* eidx0[2] = {(const int*)d_in[6], (const int*)d_in[8]};
  const int* eidx1[2] = {(const int*)d_in[7], (const int*)d_in[9]};
  const float* emb[2] = {(const float*)d_in[10], (const float*)d_in[11]};
  const float* Wself = (const float*)d_in[12];
  const float* Wneigh = (const float*)d_in[13];
  const float* Wedg = (const float*)d_in[14];
  const float* Wec = (const float*)d_in[15];
  const float* bec = (const float*)d_in[16];
  const float* fcw = (const float*)d_in[17];
  const float* fcb = (const float*)d_in[18];
  float* out = (float*)d_out;

  // workspace layout (floats), total ~5.77M floats = ~23 MB
  float* ws = (float*)d_ws;
  float* f01  = ws;                  // [5632,256]
  float* nm01 = f01  + 1441792;      // [5632,256]
  float* em01 = nm01 + 1441792;      // [5632,64]
  float* eg0  = em01 + 360448;       // [5120,64]
  float* h01  = eg0  + 327680;       // [5632,256]
  float* enew = h01  + 1441792;      // [5120,64]
  float* h1m  = enew + 327680;       // [512,256]
  float* emn  = h1m  + 131072;       // [512,64]
  float* osum = emn  + 32768;        // 2 x [512,256]

  dim3 blk(256);
  auto nb = [](int n) { return dim3((unsigned)((n + 255) / 256)); };

  for (int mp = 0; mp < 2; ++mp) {
    const float* Ws0 = Wself  + (size_t)(mp * 2 + 0) * 65536;
    const float* Ws1 = Wself  + (size_t)(mp * 2 + 1) * 65536;
    const float* Wn0 = Wneigh + (size_t)(mp * 2 + 0) * 65536;
    const float* Wn1 = Wneigh + (size_t)(mp * 2 + 1) * 65536;
    const float* Wg0 = Wedg   + (size_t)(mp * 2 + 0) * 16384;
    const float* Wg1 = Wedg   + (size_t)(mp * 2 + 1) * 16384;
    const float* We0 = Wec    + (size_t)(mp * 2 + 0) * 36864;
    const float* be0 = bec    + (size_t)(mp * 2 + 0) * 64;

    // gathers / gathered means (f32)
    gather_mean_k<<<nb(512 * 64), blk, 0, stream>>>(f01, feats, ids, 512, 64, 1, 1.0f);
    gather_mean_k<<<nb(5120 * 64), blk, 0, stream>>>(f01 + 512 * 256, feats, nidx0[mp], 5120, 64, 1, 1.0f);
    gather_mean_k<<<nb(512 * 64), blk, 0, stream>>>(nm01, feats, nidx0[mp], 512, 64, NS, 0.1f);
    gather_mean_k<<<nb(5120 * 64), blk, 0, stream>>>(nm01 + 512 * 256, feats, nidx1[mp], 5120, 64, NS, 0.1f);
    gather_mean_k<<<nb(512 * 16), blk, 0, stream>>>(em01, emb[mp], eidx0[mp], 512, 16, NS, 0.1f);
    gather_mean_k<<<nb(5120 * 16), blk, 0, stream>>>(em01 + 512 * 64, emb[mp], eidx1[mp], 5120, 16, NS, 0.1f);
    gather_mean_k<<<nb(5120 * 16), blk, 0, stream>>>(eg0, emb[mp], eidx0[mp], 5120, 16, 1, 1.0f);

    // layer 0 agg: h01 = relu(f01@Ws0 + nm01@Wn0 + em01@Wg0)  [5632,256]
    gemm3_k<1, false><<<dim3(4, 88), blk, 0, stream>>>(
        f01, Ws0, 256, 1, nm01, Wn0, 256, 1, em01, Wg0, 64, 1,
        nullptr, h01, 256);

    // edge update: enew = tanh([h0(rep S) | h1 | eg0] @ We0 + be0)  [5120,64]
    gemm3_k<2, true><<<dim3(1, 80), blk, 0, stream>>>(
        h01, We0, 256, NS, h01 + 512 * 256, We0 + 256 * 64, 256, 1,
        eg0, We0 + 512 * 64, 64, 1, be0, enew, 64);

    // means over S for layer 1
    mean_rows_k<<<nb(512 * 64), blk, 0, stream>>>(h1m, h01 + 512 * 256, 512, 64);
    mean_rows_k<<<nb(512 * 16), blk, 0, stream>>>(emn, enew, 512, 16);

    // layer 1 agg (identity act): osum_mp = h0@Ws1 + h1m@Wn1 + emn@Wg1  [512,256]
    gemm3_k<0, false><<<dim3(4, 8), blk, 0, stream>>>(
        h01, Ws1, 256, 1, h1m, Wn1, 256, 1, emn, Wg1, 64, 1,
        nullptr, osum + (size_t)mp * 131072, 256);
  }

  // metapath mean + L2 normalize + FC -> f32 out [512,8]
  finalize_k<<<dim3(512), dim3(64), 0, stream>>>(osum, osum + 131072, fcw, fcb, out);
}

// Round 3
// 325.137 us; speedup vs baseline: 1.7871x; 1.7871x over previous
//
#include <hip/hip_runtime.h>

#define NS 10

typedef __attribute__((ext_vector_type(8))) short bf16x8;
typedef __attribute__((ext_vector_type(4))) float f32x4;

__device__ __forceinline__ unsigned short f2bf(float f) {
  union { float f; unsigned int i; } x; x.f = f;
  unsigned int r = x.i + 0x7FFFu + ((x.i >> 16) & 1u);
  return (unsigned short)(r >> 16);
}
__device__ __forceinline__ unsigned pk2(float a, float b) {
  return (unsigned)f2bf(a) | ((unsigned)f2bf(b) << 16);
}

// ================= weight pack: fp32 [K][N] -> bf16 [N][K] ==================
// wt1: [mp*2+l][256][576] (cols: Ws 0-255 | Wn 256-511 | Wedge 512-575)
// wte: [mp][64][576] from We[mp][0]
__global__ __launch_bounds__(256) void pack_w_k(
    const float* __restrict__ Wself, const float* __restrict__ Wneigh,
    const float* __restrict__ Wedg, const float* __restrict__ Wec,
    unsigned short* __restrict__ wt1, unsigned short* __restrict__ wte) {
  int t = blockIdx.x * 256 + threadIdx.x;
  const int total1 = 2 * 2 * 256 * 576;
  if (t < total1) {
    int g = t / 147456, r = t - g * 147456;
    int n = r / 576, k = r - n * 576;
    float v;
    if (k < 256) v = Wself[(long)g * 65536 + k * 256 + n];
    else if (k < 512) v = Wneigh[(long)g * 65536 + (k - 256) * 256 + n];
    else v = Wedg[(long)g * 16384 + (k - 512) * 256 + n];
    wt1[t] = f2bf(v);
  } else {
    int t2 = t - total1;  // < 2*64*576
    int mp = t2 / 36864, r = t2 - mp * 36864;
    int n = r / 576, k = r - n * 576;
    wte[t2] = f2bf(Wec[(long)(mp * 2) * 36864 + k * 64 + n]);
  }
}

// ================= gather / gather-mean uber-kernel =========================
struct GJob {
  const float* table; const int* idx; float* out;
  int M, D4, ns, ostride; float inv; int blk0;
};
struct GJobs { GJob j[14]; };

__global__ __launch_bounds__(256) void gather_k(GJobs js, int njobs) {
  int b = blockIdx.x, ji = 0;
  for (int k = 1; k < njobs; ++k) if (b >= js.j[k].blk0) ji = k;
  GJob jb = js.j[ji];
  int t = (b - jb.blk0) * 256 + threadIdx.x;
  if (t >= jb.M * jb.D4) return;
  int m = t / jb.D4, d4 = t - m * jb.D4;
  long D = (long)jb.D4 * 4;
  float ax = 0.f, ay = 0.f, az = 0.f, aw = 0.f;
  for (int s = 0; s < jb.ns; ++s) {
    long r = jb.idx ? (long)jb.idx[(long)m * jb.ns + s] : ((long)m * jb.ns + s);
    float4 v = *(const float4*)(jb.table + r * D + d4 * 4);
    ax += v.x; ay += v.y; az += v.z; aw += v.w;
  }
  float4 o; o.x = ax * jb.inv; o.y = ay * jb.inv; o.z = az * jb.inv; o.w = aw * jb.inv;
  *(float4*)(jb.out + (long)m * jb.ostride + d4 * 4) = o;
}

// ================= MFMA GEMM: C = act(sum_seg A_seg @ Wt^T + bias) ==========
// A segs fp32 (row map r -> r/dv), Wt bf16 [N][Ktot] n-major, C fp32 [M][N].
// BM=128, BN in {128,64}; 256 threads = 4 waves, 2x2 wave grid,
// wave-tile = 64 x BN/2 of 16x16x32 mfma tiles. blockIdx.z = metapath.
template<int BN, int ACT, bool BIAS>  // ACT: 0 none, 1 relu, 2 tanh
__global__ __launch_bounds__(256) void gemm_mfma_k(
    const float* A0, long as0, int K0, int dv0,
    const float* A1, long as1, int K1, int dv1,
    const float* A2, long as2, int K2, int dv2,
    const unsigned short* Bt, long bs, int Ktot,
    const float* bias, long biass,
    float* C, long cs, int N) {
  constexpr int TN = BN / 32;
  __shared__ unsigned short As[128 * 40];
  __shared__ unsigned short Bs[BN * 40];
  int tid = threadIdx.x;
  int mp = blockIdx.z;
  int n0 = blockIdx.x * BN, m0 = blockIdx.y * 128;
  const unsigned short* Bp = Bt + (long)mp * bs;

  f32x4 acc[4][TN];
#pragma unroll
  for (int i = 0; i < 4; ++i)
#pragma unroll
    for (int j = 0; j < TN; ++j) acc[i][j] = (f32x4){0.f, 0.f, 0.f, 0.f};

  const float* Asg[3] = {A0 + (long)mp * as0, A1 + (long)mp * as1, A2 + (long)mp * as2};
  const int Ksg[3] = {K0, K1, K2};
  const int Dsg[3] = {dv0, dv1, dv2};

  int wave = tid >> 6, lane = tid & 63;
  int wm = wave >> 1, wn = wave & 1;
  int quad = lane >> 4, r16 = lane & 15;

  int kbase = 0;
  for (int sg = 0; sg < 3; ++sg) {
    const float* A = Asg[sg];
    int K = Ksg[sg], dv = Dsg[sg];
    for (int k0 = 0; k0 < K; k0 += 32) {
      // ---- A stage: 128 rows x 32 k, fp32 -> bf16 LDS (row-major, pad 40)
      {
        int row = tid >> 1, half = tid & 1;
        int gr = m0 + row;
        int ar = (dv > 1) ? (gr / dv) : gr;
        const float* p = A + (long)ar * K + k0 + half * 16;
        float4 v0 = *(const float4*)(p);
        float4 v1 = *(const float4*)(p + 4);
        float4 v2 = *(const float4*)(p + 8);
        float4 v3 = *(const float4*)(p + 12);
        uint4 w0 = {pk2(v0.x, v0.y), pk2(v0.z, v0.w), pk2(v1.x, v1.y), pk2(v1.z, v1.w)};
        uint4 w1 = {pk2(v2.x, v2.y), pk2(v2.z, v2.w), pk2(v3.x, v3.y), pk2(v3.z, v3.w)};
        int off = row * 40 + half * 16;
        *(uint4*)&As[off] = w0;
        *(uint4*)&As[off + 8] = w1;
      }
      // ---- B stage: BN cols x 32 k bf16 (col-major rows, pad 40)
      if (BN == 128) {
        int col = tid >> 1, half = tid & 1;
        const unsigned short* p = Bp + (long)(n0 + col) * Ktot + kbase + k0 + half * 16;
        uint4 b0 = *(const uint4*)p;
        uint4 b1 = *(const uint4*)(p + 8);
        int off = col * 40 + half * 16;
        *(uint4*)&Bs[off] = b0;
        *(uint4*)&Bs[off + 8] = b1;
      } else {
        int col = tid >> 2, q = tid & 3;
        const unsigned short* p = Bp + (long)(n0 + col) * Ktot + kbase + k0 + q * 8;
        *(uint4*)&Bs[col * 40 + q * 8] = *(const uint4*)p;
      }
      __syncthreads();
      // ---- MFMA: wave (wm,wn) computes rows wm*64..+64, cols wn*BN/2..+BN/2
      bf16x8 af[4];
#pragma unroll
      for (int i = 0; i < 4; ++i)
        af[i] = *(const bf16x8*)&As[(wm * 64 + i * 16 + r16) * 40 + quad * 8];
      bf16x8 bf[TN];
#pragma unroll
      for (int j = 0; j < TN; ++j)
        bf[j] = *(const bf16x8*)&Bs[(wn * (BN / 2) + j * 16 + r16) * 40 + quad * 8];
#pragma unroll
      for (int i = 0; i < 4; ++i)
#pragma unroll
        for (int j = 0; j < TN; ++j)
          acc[i][j] = __builtin_amdgcn_mfma_f32_16x16x32_bf16(af[i], bf[j], acc[i][j], 0, 0, 0);
      __syncthreads();
    }
    kbase += K;
  }
  // ---- epilogue: C/D layout col=lane&15, row=quad*4+reg
  float* Cp = C + (long)mp * cs;
#pragma unroll
  for (int i = 0; i < 4; ++i) {
#pragma unroll
    for (int j = 0; j < TN; ++j) {
#pragma unroll
      for (int r = 0; r < 4; ++r) {
        int row = m0 + wm * 64 + i * 16 + quad * 4 + r;
        int col = n0 + wn * (BN / 2) + j * 16 + r16;
        float v = acc[i][j][r];
        if (BIAS) v += bias[mp * biass + col];
        if (ACT == 1) v = fmaxf(v, 0.f);
        if (ACT == 2) v = tanhf(v);
        Cp[(long)row * N + col] = v;
      }
    }
  }
}

// ---- finalize: out = normalize((o0+o1)/2) @ fc_w + fc_b, f32 out ----
__global__ __launch_bounds__(64) void finalize_k(
    const float* __restrict__ o0, const float* __restrict__ o1,
    const float* __restrict__ fcw, const float* __restrict__ fcb,
    float* __restrict__ out) {
  int b = blockIdx.x, l = threadIdx.x;
  float v[4];
  float ss = 0.f;
#pragma unroll
  for (int k = 0; k < 4; ++k) {
    int j = l + 64 * k;
    v[k] = 0.5f * (o0[(long)b * 256 + j] + o1[(long)b * 256 + j]);
    ss += v[k] * v[k];
  }
#pragma unroll
  for (int off = 32; off > 0; off >>= 1) ss += __shfl_down(ss, off);
  ss = __shfl(ss, 0);
  float sc = 1.f / fmaxf(sqrtf(ss), 1e-12f);
  float p[8];
#pragma unroll
  for (int c = 0; c < 8; ++c) p[c] = 0.f;
#pragma unroll
  for (int k = 0; k < 4; ++k) {
    int j = l + 64 * k;
    float vh = v[k] * sc;
#pragma unroll
    for (int c = 0; c < 8; ++c) p[c] += vh * fcw[j * 8 + c];
  }
#pragma unroll
  for (int off = 32; off > 0; off >>= 1) {
#pragma unroll
    for (int c = 0; c < 8; ++c) p[c] += __shfl_down(p[c], off);
  }
  if (l == 0) {
#pragma unroll
    for (int c = 0; c < 8; ++c) out[b * 8 + c] = p[c] + fcb[c];
  }
}

extern "C" void kernel_launch(void* const* d_in, const int* in_sizes, int n_in,
                              void* d_out, int out_size, void* d_ws, size_t ws_size,
                              hipStream_t stream) {
  const int* ids = (const int*)d_in[0];
  const float* feats = (const float*)d_in[1];
  const int* n0i[2] = {(const int*)d_in[2], (const int*)d_in[4]};
  const int* n1i[2] = {(const int*)d_in[3], (const int*)d_in[5]};
  const int* e0i[2] = {(const int*)d_in[6], (const int*)d_in[8]};
  const int* e1i[2] = {(const int*)d_in[7], (const int*)d_in[9]};
  const float* emb[2] = {(const float*)d_in[10], (const float*)d_in[11]};
  const float* Wself = (const float*)d_in[12];
  const float* Wneigh = (const float*)d_in[13];
  const float* Wedg = (const float*)d_in[14];
  const float* Wec = (const float*)d_in[15];
  const float* bec = (const float*)d_in[16];
  const float* fcw = (const float*)d_in[17];
  const float* fcb = (const float*)d_in[18];
  float* out = (float*)d_out;

  // ---- workspace (floats) ----
  float* ws = (float*)d_ws;
  float* A1   = ws;                    // [2][5632][576]
  float* eg0  = A1 + 6488064;          // [2][5120][64]
  float* h01  = eg0 + 655360;          // [2][5632][256]
  float* enew = h01 + 2883584;         // [2][5120][64]
  float* h1m  = enew + 655360;         // [2][512][256]
  float* emn  = h1m + 262144;          // [2][512][64]
  float* osum = emn + 65536;           // [2][512][256]
  unsigned short* wt1 = (unsigned short*)(osum + 262144);  // [4][256][576] bf16
  unsigned short* wte = wt1 + 589824;                      // [2][64][576] bf16

  // 1) pack weights -> bf16 transposed
  pack_w_k<<<dim3((589824 + 73728) / 256), dim3(256), 0, stream>>>(
      Wself, Wneigh, Wedg, Wec, wt1, wte);

  // 2) all gathers: A1 = [x_self | neigh_mean | edge_mean], eg0 = emb[e0]
  {
    GJobs gj; int blk = 0, nj = 0;
    auto add = [&](const float* table, const int* idx, float* o,
                   int M, int D4, int ns, int ostride, float inv) {
      gj.j[nj] = {table, idx, o, M, D4, ns, ostride, inv, blk};
      blk += (M * D4) / 256; ++nj;
    };
    for (int mp = 0; mp < 2; ++mp) {
      float* Am = A1 + (size_t)mp * 5632 * 576;
      add(feats, ids,     Am,                  512, 64, 1, 576, 1.0f);
      add(feats, n0i[mp], Am + 512 * 576,      5120, 64, 1, 576, 1.0f);
      add(feats, n0i[mp], Am + 256,            512, 64, NS, 576, 0.1f);
      add(feats, n1i[mp], Am + 512 * 576 + 256, 5120, 64, NS, 576, 0.1f);
      add(emb[mp], e0i[mp], Am + 512,           512, 16, NS, 576, 0.1f);
      add(emb[mp], e1i[mp], Am + 512 * 576 + 512, 5120, 16, NS, 576, 0.1f);
      add(emb[mp], e0i[mp], eg0 + (size_t)mp * 327680, 5120, 16, 1, 64, 1.0f);
    }
    gather_k<<<dim3(blk), dim3(256), 0, stream>>>(gj, nj);
  }

  // 3) layer-0 agg: h01 = relu(A1 @ WT1[mp][0])  [2][5632][256]
  gemm_mfma_k<128, 1, false><<<dim3(2, 44, 2), dim3(256), 0, stream>>>(
      A1, 5632L * 576, 576, 1, A1, 0, 0, 1, A1, 0, 0, 1,
      wt1, 2L * 147456, 576, nullptr, 0, h01, 5632L * 256, 256);

  // 4) edge update: enew = tanh([h0/10 | h1 | eg0] @ WTe + be)  [2][5120][64]
  gemm_mfma_k<64, 2, true><<<dim3(1, 40, 2), dim3(256), 0, stream>>>(
      h01, 5632L * 256, 256, 10, h01 + 512 * 256, 5632L * 256, 256, 1,
      eg0, 5120L * 64, 64, 1,
      wte, 36864L, 576, bec, 128, enew, 5120L * 64, 64);

  // 5) means over S for layer 1 (h1m, emn)
  {
    GJobs gj; int blk = 0, nj = 0;
    auto add = [&](const float* table, float* o, int M, int D4, int ostride) {
      gj.j[nj] = {table, nullptr, o, M, D4, NS, ostride, 0.1f, blk};
      blk += (M * D4) / 256; ++nj;
    };
    for (int mp = 0; mp < 2; ++mp) {
      add(h01 + (size_t)mp * 5632 * 256 + 512 * 256, h1m + (size_t)mp * 131072, 512, 64, 256);
      add(enew + (size_t)mp * 327680, emn + (size_t)mp * 32768, 512, 16, 64);
    }
    gather_k<<<dim3(blk), dim3(256), 0, stream>>>(gj, nj);
  }

  // 6) layer-1 agg: osum = [h0 | h1m | emn] @ WT1[mp][1]  [2][512][256]
  gemm_mfma_k<128, 0, false><<<dim3(2, 4, 2), dim3(256), 0, stream>>>(
      h01, 5632L * 256, 256, 1, h1m, 512L * 256, 256, 1, emn, 512L * 64, 64, 1,
      wt1 + 147456, 2L * 147456, 576, nullptr, 0, osum, 131072L, 256);

  // 7) metapath mean + L2 normalize + FC
  finalize_k<<<dim3(512), dim3(64), 0, stream>>>(osum, osum + 131072, fcw, fcb, out);
}

// Round 4
// 301.877 us; speedup vs baseline: 1.9247x; 1.0770x over previous
//
#include <hip/hip_runtime.h>

#define NS 10

typedef __attribute__((ext_vector_type(8))) short bf16x8;
typedef __attribute__((ext_vector_type(4))) float f32x4;

__device__ __forceinline__ float bf2f(unsigned short u) {
  union { unsigned int i; float f; } x;
  x.i = ((unsigned int)u) << 16;
  return x.f;
}
__device__ __forceinline__ unsigned short f2bf(float f) {
  union { float f; unsigned int i; } x; x.f = f;
  unsigned int r = x.i + 0x7FFFu + ((x.i >> 16) & 1u);
  return (unsigned short)(r >> 16);
}
__device__ __forceinline__ unsigned pk2(float a, float b) {
  return (unsigned)f2bf(a) | ((unsigned)f2bf(b) << 16);
}

// ================= weight pack: fp32 [K][N] -> bf16 [N][K] ==================
// wt1: [mp*2+l][256][576] (cols: Ws 0-255 | Wn 256-511 | Wedge 512-575)
// wte: [mp][64][576] from We[mp][0]
__global__ __launch_bounds__(256) void pack_w_k(
    const float* __restrict__ Wself, const float* __restrict__ Wneigh,
    const float* __restrict__ Wedg, const float* __restrict__ Wec,
    unsigned short* __restrict__ wt1, unsigned short* __restrict__ wte) {
  int t = blockIdx.x * 256 + threadIdx.x;
  const int total1 = 2 * 2 * 256 * 576;
  if (t < total1) {
    int g = t / 147456, r = t - g * 147456;
    int n = r / 576, k = r - n * 576;
    float v;
    if (k < 256) v = Wself[(long)g * 65536 + k * 256 + n];
    else if (k < 512) v = Wneigh[(long)g * 65536 + (k - 256) * 256 + n];
    else v = Wedg[(long)g * 16384 + (k - 512) * 256 + n];
    wt1[t] = f2bf(v);
  } else {
    int t2 = t - total1;  // < 2*64*576
    int mp = t2 / 36864, r = t2 - mp * 36864;
    int n = r / 576, k = r - n * 576;
    wte[t2] = f2bf(Wec[(long)(mp * 2) * 36864 + k * 64 + n]);
  }
}

// ================= gather / gather-mean uber-kernel (out = bf16) ============
struct GJob {
  const void* table; const int* idx; unsigned short* out;
  int M, D4, ns, ostride, bf16in, blk0; float inv;
};
struct GJobs { GJob j[14]; };

__global__ __launch_bounds__(256) void gather_k(GJobs js, int njobs) {
  int b = blockIdx.x, ji = 0;
  for (int k = 1; k < njobs; ++k) if (b >= js.j[k].blk0) ji = k;
  GJob jb = js.j[ji];
  int t = (b - jb.blk0) * 256 + threadIdx.x;
  if (t >= jb.M * jb.D4) return;
  int m = t / jb.D4, d4 = t - m * jb.D4;
  long D = (long)jb.D4 * 4;
  float ax = 0.f, ay = 0.f, az = 0.f, aw = 0.f;
  if (jb.bf16in) {
    const unsigned short* tb = (const unsigned short*)jb.table;
    for (int s = 0; s < jb.ns; ++s) {
      long r = jb.idx ? (long)jb.idx[(long)m * jb.ns + s] : ((long)m * jb.ns + s);
      uint2 v = *(const uint2*)(tb + r * D + d4 * 4);
      ax += bf2f((unsigned short)(v.x & 0xFFFF)); ay += bf2f((unsigned short)(v.x >> 16));
      az += bf2f((unsigned short)(v.y & 0xFFFF)); aw += bf2f((unsigned short)(v.y >> 16));
    }
  } else {
    const float* tb = (const float*)jb.table;
    for (int s = 0; s < jb.ns; ++s) {
      long r = jb.idx ? (long)jb.idx[(long)m * jb.ns + s] : ((long)m * jb.ns + s);
      float4 v = *(const float4*)(tb + r * D + d4 * 4);
      ax += v.x; ay += v.y; az += v.z; aw += v.w;
    }
  }
  uint2 o; o.x = pk2(ax * jb.inv, ay * jb.inv); o.y = pk2(az * jb.inv, aw * jb.inv);
  *(uint2*)(jb.out + (long)m * jb.ostride + d4 * 4) = o;
}

// ================= MFMA GEMM: C = act(sum_seg A_seg @ Wt^T + bias) ==========
// A segs bf16 (row map r -> r/dv, strides in shorts), Wt bf16 [N][Ktot],
// C bf16 or fp32 [M][N]. BM=128, BN in {128,64}; 256 threads = 4 waves,
// 2x2 wave grid, wave-tile 64 x BN/2. blockIdx.z = metapath.
template<int BN, int ACT, bool BIAS, bool OUTBF>  // ACT: 0 none, 1 relu, 2 tanh
__global__ __launch_bounds__(256) void gemm_mfma_k(
    const unsigned short* A0, long as0, int K0, int dv0,
    const unsigned short* A1, long as1, int K1, int dv1,
    const unsigned short* A2, long as2, int K2, int dv2,
    const unsigned short* Bt, long bs, int Ktot,
    const float* bias, long biass,
    void* Cv, long cs, int N) {
  constexpr int TN = BN / 32;
  __shared__ unsigned short As[128 * 40];
  __shared__ unsigned short Bs[BN * 40];
  int tid = threadIdx.x;
  int mp = blockIdx.z;
  int n0 = blockIdx.x * BN, m0 = blockIdx.y * 128;
  const unsigned short* Bp = Bt + (long)mp * bs;

  f32x4 acc[4][TN];
#pragma unroll
  for (int i = 0; i < 4; ++i)
#pragma unroll
    for (int j = 0; j < TN; ++j) acc[i][j] = (f32x4){0.f, 0.f, 0.f, 0.f};

  const unsigned short* Asg[3] = {A0 + (long)mp * as0, A1 + (long)mp * as1,
                                  A2 + (long)mp * as2};
  const int Ksg[3] = {K0, K1, K2};
  const int Dsg[3] = {dv0, dv1, dv2};

  int wave = tid >> 6, lane = tid & 63;
  int wm = wave >> 1, wn = wave & 1;
  int quad = lane >> 4, r16 = lane & 15;

  int kbase = 0;
  for (int sg = 0; sg < 3; ++sg) {
    const unsigned short* A = Asg[sg];
    int K = Ksg[sg], dv = Dsg[sg];
    for (int k0 = 0; k0 < K; k0 += 32) {
      // ---- A stage: 128 rows x 32 k bf16 -> LDS (row-major, pad 40 shorts)
      {
        int row = tid >> 1, half = tid & 1;
        int gr = m0 + row;
        int ar = (dv > 1) ? (gr / dv) : gr;
        const unsigned short* p = A + (long)ar * K + k0 + half * 16;
        uint4 v0 = *(const uint4*)p;
        uint4 v1 = *(const uint4*)(p + 8);
        int off = row * 40 + half * 16;
        *(uint4*)&As[off] = v0;
        *(uint4*)&As[off + 8] = v1;
      }
      // ---- B stage: BN cols x 32 k bf16
      if (BN == 128) {
        int col = tid >> 1, half = tid & 1;
        const unsigned short* p = Bp + (long)(n0 + col) * Ktot + kbase + k0 + half * 16;
        uint4 b0 = *(const uint4*)p;
        uint4 b1 = *(const uint4*)(p + 8);
        int off = col * 40 + half * 16;
        *(uint4*)&Bs[off] = b0;
        *(uint4*)&Bs[off + 8] = b1;
      } else {
        int col = tid >> 2, q = tid & 3;
        const unsigned short* p = Bp + (long)(n0 + col) * Ktot + kbase + k0 + q * 8;
        *(uint4*)&Bs[col * 40 + q * 8] = *(const uint4*)p;
      }
      __syncthreads();
      // ---- MFMA: wave (wm,wn): rows wm*64..+64, cols wn*BN/2..+BN/2
      bf16x8 af[4];
#pragma unroll
      for (int i = 0; i < 4; ++i)
        af[i] = *(const bf16x8*)&As[(wm * 64 + i * 16 + r16) * 40 + quad * 8];
      bf16x8 bfr[TN];
#pragma unroll
      for (int j = 0; j < TN; ++j)
        bfr[j] = *(const bf16x8*)&Bs[(wn * (BN / 2) + j * 16 + r16) * 40 + quad * 8];
#pragma unroll
      for (int i = 0; i < 4; ++i)
#pragma unroll
        for (int j = 0; j < TN; ++j)
          acc[i][j] = __builtin_amdgcn_mfma_f32_16x16x32_bf16(af[i], bfr[j], acc[i][j], 0, 0, 0);
      __syncthreads();
    }
    kbase += K;
  }
  // ---- epilogue: C/D layout col=lane&15, row=quad*4+reg
#pragma unroll
  for (int i = 0; i < 4; ++i) {
#pragma unroll
    for (int j = 0; j < TN; ++j) {
#pragma unroll
      for (int r = 0; r < 4; ++r) {
        int row = m0 + wm * 64 + i * 16 + quad * 4 + r;
        int col = n0 + wn * (BN / 2) + j * 16 + r16;
        float v = acc[i][j][r];
        if (BIAS) v += bias[mp * biass + col];
        if (ACT == 1) v = fmaxf(v, 0.f);
        if (ACT == 2) v = tanhf(v);
        if (OUTBF)
          ((unsigned short*)Cv)[(long)mp * cs + (long)row * N + col] = f2bf(v);
        else
          ((float*)Cv)[(long)mp * cs + (long)row * N + col] = v;
      }
    }
  }
}

// ---- finalize: out = normalize((o0+o1)/2) @ fc_w + fc_b, f32 out ----
__global__ __launch_bounds__(64) void finalize_k(
    const float* __restrict__ o0, const float* __restrict__ o1,
    const float* __restrict__ fcw, const float* __restrict__ fcb,
    float* __restrict__ out) {
  int b = blockIdx.x, l = threadIdx.x;
  float v[4];
  float ss = 0.f;
#pragma unroll
  for (int k = 0; k < 4; ++k) {
    int j = l + 64 * k;
    v[k] = 0.5f * (o0[(long)b * 256 + j] + o1[(long)b * 256 + j]);
    ss += v[k] * v[k];
  }
#pragma unroll
  for (int off = 32; off > 0; off >>= 1) ss += __shfl_down(ss, off);
  ss = __shfl(ss, 0);
  float sc = 1.f / fmaxf(sqrtf(ss), 1e-12f);
  float p[8];
#pragma unroll
  for (int c = 0; c < 8; ++c) p[c] = 0.f;
#pragma unroll
  for (int k = 0; k < 4; ++k) {
    int j = l + 64 * k;
    float vh = v[k] * sc;
#pragma unroll
    for (int c = 0; c < 8; ++c) p[c] += vh * fcw[j * 8 + c];
  }
#pragma unroll
  for (int off = 32; off > 0; off >>= 1) {
#pragma unroll
    for (int c = 0; c < 8; ++c) p[c] += __shfl_down(p[c], off);
  }
  if (l == 0) {
#pragma unroll
    for (int c = 0; c < 8; ++c) out[b * 8 + c] = p[c] + fcb[c];
  }
}

extern "C" void kernel_launch(void* const* d_in, const int* in_sizes, int n_in,
                              void* d_out, int out_size, void* d_ws, size_t ws_size,
                              hipStream_t stream) {
  const int* ids = (const int*)d_in[0];
  const float* feats = (const float*)d_in[1];
  const int* n0i[2] = {(const int*)d_in[2], (const int*)d_in[4]};
  const int* n1i[2] = {(const int*)d_in[3], (const int*)d_in[5]};
  const int* e0i[2] = {(const int*)d_in[6], (const int*)d_in[8]};
  const int* e1i[2] = {(const int*)d_in[7], (const int*)d_in[9]};
  const float* emb[2] = {(const float*)d_in[10], (const float*)d_in[11]};
  const float* Wself = (const float*)d_in[12];
  const float* Wneigh = (const float*)d_in[13];
  const float* Wedg = (const float*)d_in[14];
  const float* Wec = (const float*)d_in[15];
  const float* bec = (const float*)d_in[16];
  const float* fcw = (const float*)d_in[17];
  const float* fcb = (const float*)d_in[18];
  float* out = (float*)d_out;

  // ---- workspace: fp32 osum first, then bf16 buffers ----
  float* osum = (float*)d_ws;                       // [2][512][256] f32
  unsigned short* A1b  = (unsigned short*)(osum + 262144);  // [2][5632][576]
  unsigned short* eg0  = A1b + 6488064;             // [2][5120][64]
  unsigned short* h01  = eg0 + 655360;              // [2][5632][256]
  unsigned short* enew = h01 + 2883584;             // [2][5120][64]
  unsigned short* h1m  = enew + 655360;             // [2][512][256]
  unsigned short* emn  = h1m + 262144;              // [2][512][64]
  unsigned short* wt1  = emn + 65536;               // [4][256][576]
  unsigned short* wte  = wt1 + 589824;              // [2][64][576]

  // 1) pack weights -> bf16 transposed
  pack_w_k<<<dim3((589824 + 73728) / 256), dim3(256), 0, stream>>>(
      Wself, Wneigh, Wedg, Wec, wt1, wte);

  // 2) all gathers: A1 = [x_self | neigh_mean | edge_mean], eg0 = emb[e0]
  {
    GJobs gj; int blk = 0, nj = 0;
    auto add = [&](const void* table, const int* idx, unsigned short* o,
                   int M, int D4, int ns, int ostride, float inv) {
      gj.j[nj] = {table, idx, o, M, D4, ns, ostride, 0, blk, inv};
      blk += (M * D4) / 256; ++nj;
    };
    for (int mp = 0; mp < 2; ++mp) {
      unsigned short* Am = A1b + (size_t)mp * 5632 * 576;
      add(feats, ids,     Am,                    512, 64, 1, 576, 1.0f);
      add(feats, n0i[mp], Am + 512 * 576,        5120, 64, 1, 576, 1.0f);
      add(feats, n0i[mp], Am + 256,              512, 64, NS, 576, 0.1f);
      add(feats, n1i[mp], Am + 512 * 576 + 256,  5120, 64, NS, 576, 0.1f);
      add(emb[mp], e0i[mp], Am + 512,            512, 16, NS, 576, 0.1f);
      add(emb[mp], e1i[mp], Am + 512 * 576 + 512, 5120, 16, NS, 576, 0.1f);
      add(emb[mp], e0i[mp], eg0 + (size_t)mp * 327680, 5120, 16, 1, 64, 1.0f);
    }
    gather_k<<<dim3(blk), dim3(256), 0, stream>>>(gj, nj);
  }

  // 3) layer-0 agg: h01 = relu(A1 @ WT1[mp][0])  [2][5632][256] bf16
  gemm_mfma_k<128, 1, false, true><<<dim3(2, 44, 2), dim3(256), 0, stream>>>(
      A1b, 5632L * 576, 576, 1, A1b, 0, 0, 1, A1b, 0, 0, 1,
      wt1, 2L * 147456, 576, nullptr, 0, h01, 5632L * 256, 256);

  // 4) edge update: enew = tanh([h0(rep10) | h1 | eg0] @ WTe + be) [2][5120][64]
  gemm_mfma_k<64, 2, true, true><<<dim3(1, 40, 2), dim3(256), 0, stream>>>(
      h01, 5632L * 256, 256, 10, h01 + 512 * 256, 5632L * 256, 256, 1,
      eg0, 5120L * 64, 64, 1,
      wte, 36864L, 576, bec, 128, enew, 5120L * 64, 64);

  // 5) means over S for layer 1 (h1m, emn) — bf16 in/out
  {
    GJobs gj; int blk = 0, nj = 0;
    auto add = [&](const unsigned short* table, unsigned short* o, int M, int D4,
                   int ostride) {
      gj.j[nj] = {table, nullptr, o, M, D4, NS, ostride, 1, blk, 0.1f};
      blk += (M * D4) / 256; ++nj;
    };
    for (int mp = 0; mp < 2; ++mp) {
      add(h01 + (size_t)mp * 5632 * 256 + 512 * 256, h1m + (size_t)mp * 131072, 512, 64, 256);
      add(enew + (size_t)mp * 327680, emn + (size_t)mp * 32768, 512, 16, 64);
    }
    gather_k<<<dim3(blk), dim3(256), 0, stream>>>(gj, nj);
  }

  // 6) layer-1 agg: osum = [h0 | h1m | emn] @ WT1[mp][1]  [2][512][256] f32
  gemm_mfma_k<128, 0, false, false><<<dim3(2, 4, 2), dim3(256), 0, stream>>>(
      h01, 5632L * 256, 256, 1, h1m, 512L * 256, 256, 1, emn, 512L * 64, 64, 1,
      wt1 + 147456, 2L * 147456, 576, nullptr, 0, osum, 131072L, 256);

  // 7) metapath mean + L2 normalize + FC
  finalize_k<<<dim3(512), dim3(64), 0, stream>>>(osum, osum + 131072, fcw, fcb, out);
}